// Round 2
// baseline (902.918 us; speedup 1.0000x reference)
//
#include <hip/hip_runtime.h>
#include <hip/hip_bf16.h>

// ---------------- problem constants ----------------
#define BATCH   256
#define NTOK    50          // 49 patches + CLS
#define NPATCH  49
#define HID     256
#define HEADS   8
#define DH      32
#define NBLK    4
#define MLPD    1024
#define OUTD    1000
#define KPATCH  3072        // 3*32*32
#define MROWS   (BATCH*NTOK)     // 12800
#define MPATCH  (BATCH*NPATCH)   // 12544

typedef __attribute__((ext_vector_type(4))) float  floatx4;
typedef __attribute__((ext_vector_type(8))) __bf16 bf16x8;
typedef __attribute__((ext_vector_type(4))) int    int4v;

// Runtime input-dtype detection: ln1_g is all-ones. First 16-bit word is
// 0x3F80 iff the float inputs are bf16; fp32 gives 0x0000 (low mantissa).
__device__ __forceinline__ bool tag_is_bf16(const unsigned short* tag) {
    return tag[0] == 0x3F80u;
}
__device__ __forceinline__ float ldf(const void* p, long i, bool bf) {
    return bf ? __bfloat162float(((const __hip_bfloat16*)p)[i])
              : ((const float*)p)[i];
}

// packed small-param layout (bf16 canonical), offsets in elements
#define OFF_BMAP 0
#define OFF_CLS  256
#define OFF_ASRC 512
#define OFF_ADST 1536
#define OFF_BGAT 2560
#define OFF_LN1G 3584
#define OFF_LN1B 4608
#define OFF_LN2G 5632
#define OFF_LN2B 6656
#define OFF_B1   7680
#define OFF_B2   11776
#define OFF_BOUT 12800
#define SP_TOTAL 13800

struct SmallSrc {
    const void *bmap, *cls, *asrc, *adst, *bgat, *ln1g, *ln1b, *ln2g, *ln2b, *b1, *b2, *bout;
};

__global__ void pack_params(SmallSrc s, const unsigned short* tag,
                            __hip_bfloat16* __restrict__ sp) {
    bool bf = tag_is_bf16(tag);
    int idx = blockIdx.x * 256 + threadIdx.x;
    if (idx >= SP_TOTAL) return;
    const void* src; long off;
    if      (idx < OFF_CLS)  { src = s.bmap; off = idx; }
    else if (idx < OFF_ASRC) { src = s.cls;  off = idx - OFF_CLS; }
    else if (idx < OFF_ADST) { src = s.asrc; off = idx - OFF_ASRC; }
    else if (idx < OFF_BGAT) { src = s.adst; off = idx - OFF_ADST; }
    else if (idx < OFF_LN1G) { src = s.bgat; off = idx - OFF_BGAT; }
    else if (idx < OFF_LN1B) { src = s.ln1g; off = idx - OFF_LN1G; }
    else if (idx < OFF_LN2G) { src = s.ln1b; off = idx - OFF_LN1B; }
    else if (idx < OFF_LN2B) { src = s.ln2g; off = idx - OFF_LN2G; }
    else if (idx < OFF_B1)   { src = s.ln2b; off = idx - OFF_LN2B; }
    else if (idx < OFF_B2)   { src = s.b1;   off = idx - OFF_B1; }
    else if (idx < OFF_BOUT) { src = s.b2;   off = idx - OFF_B2; }
    else                     { src = s.bout; off = idx - OFF_BOUT; }
    sp[idx] = __float2bfloat16(ldf(src, off, bf));
}

// =====================================================================
// prep: block 0 builds dense adjacency (with multiplicity + self loops),
// blocks 1..50 build the sinusoidal positional table (fp32).
// edge_index may arrive as int32 or int64; detect at runtime (all src>=1).
// =====================================================================
__global__ void prep_kernel(const int* __restrict__ ei, int E0,
                            float* __restrict__ adj, float* __restrict__ pe) {
    int tid = threadIdx.x;
    if (blockIdx.x == 0) {
        for (int i = tid; i < NTOK * NTOK; i += 64) adj[i] = 0.f;
        __syncthreads();
        bool is64 = (ei[1] == 0);   // int64 little-endian high word
        for (int e = tid; e < E0; e += 64) {
            int s, d;
            if (is64) { s = ei[2 * e]; d = ei[2 * (E0 + e)]; }
            else      { s = ei[e];     d = ei[E0 + e]; }
            if ((unsigned)s < NTOK && (unsigned)d < NTOK)   // clamp: never corrupt ws
                atomicAdd(&adj[d * NTOK + s], 1.f);
        }
        if (tid < NTOK) atomicAdd(&adj[tid * NTOK + tid], 1.f);  // self loops
    } else {
        int t = blockIdx.x - 1;
        for (int j = tid; j < HID; j += 64) {
            float jeff = (float)(j & ~1);
            float ang = (float)t / powf(10000.f, jeff / (float)HID);
            pe[t * HID + j] = ((j & 1) == 0) ? sinf(ang) : cosf(ang);
        }
    }
}

// =====================================================================
// dtype-aware transpose of all weights to [N][K] canonical bf16
// =====================================================================
__global__ void transpose_kernel(
    const void* __restrict__ Wmap, const void* __restrict__ Wgat,
    const void* __restrict__ W1,   const void* __restrict__ W2,
    const void* __restrict__ Wout, const unsigned short* tag,
    __hip_bfloat16* __restrict__ wmapT, __hip_bfloat16* __restrict__ wgatT,
    __hip_bfloat16* __restrict__ w1T,   __hip_bfloat16* __restrict__ w2T,
    __hip_bfloat16* __restrict__ woutT) {
    bool bf = tag_is_bf16(tag);
    int idx = blockIdx.x * 256 + threadIdx.x;
    if (idx < 786432) {                     // Wmap [3072][256] -> [256][3072]
        int r = idx >> 8, c = idx & 255;
        wmapT[c * 3072 + r] = __float2bfloat16(ldf(Wmap, idx, bf)); return;
    }
    idx -= 786432;
    if (idx < 262144) {                     // Wgat [4][256][256]
        int l = idx >> 16, rem = idx & 65535, r = rem >> 8, c = rem & 255;
        wgatT[l * 65536 + c * 256 + r] = __float2bfloat16(ldf(Wgat, idx, bf)); return;
    }
    idx -= 262144;
    if (idx < 1048576) {                    // W1 [4][256][1024] -> [4][1024][256]
        int l = idx >> 18, rem = idx & 262143, r = rem >> 10, c = rem & 1023;
        w1T[l * 262144 + c * 256 + r] = __float2bfloat16(ldf(W1, idx, bf)); return;
    }
    idx -= 1048576;
    if (idx < 1048576) {                    // W2 [4][1024][256] -> [4][256][1024]
        int l = idx >> 18, rem = idx & 262143, r = rem >> 8, c = rem & 255;
        w2T[l * 262144 + c * 1024 + r] = __float2bfloat16(ldf(W2, idx, bf)); return;
    }
    idx -= 1048576;
    if (idx < 256000) {                     // Wout [256][1000] -> [1000][256]
        int r = idx / 1000, c = idx % 1000;
        woutT[c * 256 + r] = __float2bfloat16(ldf(Wout, idx, bf));
    }
}

// =====================================================================
// Generic MFMA GEMM: C[M,N] = A[M,K] * BT[N,K]^T  (bf16 in, fp32 acc)
// 64x64 block tile, BK=32, 4 waves each 32x32 (2x2 of 16x16x32 MFMA).
// MODE 0: outF = acc; 1: outF = acc+bias; 2: outB = bf16(gelu(acc+bias));
// MODE 3: outF += acc+bias (fused residual).  M%64==0, K%32==0 here.
// =====================================================================
template<int MODE>
__global__ __launch_bounds__(256) void gemm_kernel(
    const __hip_bfloat16* __restrict__ A, const __hip_bfloat16* __restrict__ BT,
    const __hip_bfloat16* __restrict__ bias,
    float* __restrict__ outF, __hip_bfloat16* __restrict__ outB,
    int M, int N, int K) {
    __shared__ short As[64][40];   // 80B row stride: 16B-aligned, 2-way max (free)
    __shared__ short Bs[64][40];
    int tid = threadIdx.x;
    int m0 = blockIdx.x * 64, n0 = blockIdx.y * 64;
    int arow = tid >> 2, ak = (tid & 3) * 8;
    int lane = tid & 63, wave = tid >> 6;
    int wm = (wave >> 1) * 32, wn = (wave & 1) * 32;
    int q = lane >> 4, r = lane & 15;
    const short* Ag = (const short*)A;
    const short* Bg = (const short*)BT;
    bool bvalid = (n0 + arow) < N;
    long aoff = (long)(m0 + arow) * K + ak;
    long boff = (long)(n0 + arow) * K + ak;
    floatx4 acc[2][2];
    for (int mi = 0; mi < 2; ++mi)
        for (int ni = 0; ni < 2; ++ni) acc[mi][ni] = floatx4{0.f, 0.f, 0.f, 0.f};
    int4v zero4 = {0, 0, 0, 0};
    for (int k0 = 0; k0 < K; k0 += 32) {
        int4v av = *(const int4v*)(Ag + aoff + k0);
        int4v bv = bvalid ? *(const int4v*)(Bg + boff + k0) : zero4;
        __syncthreads();
        *(int4v*)&As[arow][ak] = av;
        *(int4v*)&Bs[arow][ak] = bv;
        __syncthreads();
        bf16x8 af0 = *(const bf16x8*)&As[wm + r][q * 8];
        bf16x8 af1 = *(const bf16x8*)&As[wm + 16 + r][q * 8];
        bf16x8 bf0 = *(const bf16x8*)&Bs[wn + r][q * 8];
        bf16x8 bf1 = *(const bf16x8*)&Bs[wn + 16 + r][q * 8];
        acc[0][0] = __builtin_amdgcn_mfma_f32_16x16x32_bf16(af0, bf0, acc[0][0], 0, 0, 0);
        acc[0][1] = __builtin_amdgcn_mfma_f32_16x16x32_bf16(af0, bf1, acc[0][1], 0, 0, 0);
        acc[1][0] = __builtin_amdgcn_mfma_f32_16x16x32_bf16(af1, bf0, acc[1][0], 0, 0, 0);
        acc[1][1] = __builtin_amdgcn_mfma_f32_16x16x32_bf16(af1, bf1, acc[1][1], 0, 0, 0);
    }
    // epilogue: C/D layout col = lane&15, row = quad*4 + reg  [m89-verified]
    for (int ni = 0; ni < 2; ++ni) {
        int col = n0 + wn + ni * 16 + r;
        if (col >= N) continue;
        float bv = (MODE != 0) ? __bfloat162float(bias[col]) : 0.f;
        for (int mi = 0; mi < 2; ++mi) {
            for (int reg = 0; reg < 4; ++reg) {
                int row = m0 + wm + mi * 16 + q * 4 + reg;
                float v = acc[mi][ni][reg];
                long oi = (long)row * N + col;
                if (MODE == 0) outF[oi] = v;
                if (MODE == 1) outF[oi] = v + bv;
                if (MODE == 2) {
                    float u = v + bv;
                    float g = 0.5f * u * (1.f + erff(u * 0.70710678118654752f));
                    outB[oi] = __float2bfloat16(g);
                }
                if (MODE == 3) outF[oi] += v + bv;
            }
        }
    }
}

// =====================================================================
// Patch-embed GEMM: patchify fused into the A loader; dtype-branched images.
// A row m = b*49+p, k = c*1024 + hh*32 + ww ; one k-tile of 32 == one (c,hh)
// row segment of 32 contiguous pixels -> coalesced loads.
// Writes resid[(b*50 + p + 1)*256 + n] = acc + bmap[n]  (fp32).
// =====================================================================
__global__ __launch_bounds__(256) void patch_gemm_kernel(
    const void* __restrict__ img, const __hip_bfloat16* __restrict__ wmapT,
    const __hip_bfloat16* __restrict__ sp, const unsigned short* tag,
    float* __restrict__ resid) {
    __shared__ short As[64][40];
    __shared__ short Bs[64][40];
    bool bf = tag_is_bf16(tag);
    int tid = threadIdx.x;
    int m0 = blockIdx.x * 64, n0 = blockIdx.y * 64;
    int arow = tid >> 2, off8 = (tid & 3) * 8;
    int lane = tid & 63, wave = tid >> 6;
    int wm = (wave >> 1) * 32, wn = (wave & 1) * 32;
    int q = lane >> 4, r = lane & 15;
    int m = m0 + arow;
    int pb = m / 49, p = m % 49, pi = p / 7, pj = p % 7;
    long rowbase = ((long)(pb * 3) * 224 + pi * 32) * 224 + pj * 32;
    const short* Bg = (const short*)wmapT;
    long boff = (long)(n0 + arow) * KPATCH + off8;
    floatx4 acc[2][2];
    for (int mi = 0; mi < 2; ++mi)
        for (int ni = 0; ni < 2; ++ni) acc[mi][ni] = floatx4{0.f, 0.f, 0.f, 0.f};
    for (int kt = 0; kt < 96; ++kt) {       // K = 96*32
        long gofs = rowbase + (kt >> 5) * 50176 + (kt & 31) * 224 + off8;
        bf16x8 a8;
        if (bf) {
            a8 = *(const bf16x8*)(((const __bf16*)img) + gofs);
        } else {
            const float* f = (const float*)img;
            union { bf16x8 v; __hip_bfloat16 h[8]; } u;
#pragma unroll
            for (int j = 0; j < 8; ++j) u.h[j] = __float2bfloat16(f[gofs + j]);
            a8 = u.v;
        }
        int4v bv = *(const int4v*)(Bg + boff + (long)kt * 32);
        __syncthreads();
        *(bf16x8*)&As[arow][off8] = a8;
        *(int4v*)&Bs[arow][off8] = bv;
        __syncthreads();
        bf16x8 af0 = *(const bf16x8*)&As[wm + r][q * 8];
        bf16x8 af1 = *(const bf16x8*)&As[wm + 16 + r][q * 8];
        bf16x8 bf0 = *(const bf16x8*)&Bs[wn + r][q * 8];
        bf16x8 bf1 = *(const bf16x8*)&Bs[wn + 16 + r][q * 8];
        acc[0][0] = __builtin_amdgcn_mfma_f32_16x16x32_bf16(af0, bf0, acc[0][0], 0, 0, 0);
        acc[0][1] = __builtin_amdgcn_mfma_f32_16x16x32_bf16(af0, bf1, acc[0][1], 0, 0, 0);
        acc[1][0] = __builtin_amdgcn_mfma_f32_16x16x32_bf16(af1, bf0, acc[1][0], 0, 0, 0);
        acc[1][1] = __builtin_amdgcn_mfma_f32_16x16x32_bf16(af1, bf1, acc[1][1], 0, 0, 0);
    }
    const __hip_bfloat16* bmap = sp + OFF_BMAP;
    for (int ni = 0; ni < 2; ++ni) {
        int col = n0 + wn + ni * 16 + r;
        float bv = __bfloat162float(bmap[col]);
        for (int mi = 0; mi < 2; ++mi) {
            for (int reg = 0; reg < 4; ++reg) {
                int row = m0 + wm + mi * 16 + q * 4 + reg;
                int bb = row / 49, pp = row % 49;
                resid[(bb * NTOK + pp + 1) * HID + col] = acc[mi][ni][reg] + bv;
            }
        }
    }
}

// =====================================================================
// finish tokens: CLS row = cls + pe[0]; patch rows += pe[t]
// =====================================================================
__global__ void finish_tokens(const __hip_bfloat16* __restrict__ sp,
                              const float* __restrict__ pe, float* __restrict__ resid) {
    int idx = blockIdx.x * 256 + threadIdx.x;   // < 256*50*256
    int row = idx >> 8, n = idx & 255, t = row % NTOK;
    if (t == 0) resid[idx] = __bfloat162float(sp[OFF_CLS + n]) + pe[n];
    else        resid[idx] += pe[t * HID + n];
}

// =====================================================================
// LayerNorm: one wave per row, fp32 in -> bf16 out
// =====================================================================
__global__ __launch_bounds__(256) void ln_kernel(
    const float* __restrict__ x, const __hip_bfloat16* __restrict__ g,
    const __hip_bfloat16* __restrict__ bta, __hip_bfloat16* __restrict__ y) {
    int row = blockIdx.x * 4 + (threadIdx.x >> 6);
    int lane = threadIdx.x & 63;
    const float* xr = x + (long)row * HID;
    float v[4];
#pragma unroll
    for (int i = 0; i < 4; ++i) v[i] = xr[lane + 64 * i];
    float s = v[0] + v[1] + v[2] + v[3];
#pragma unroll
    for (int off = 32; off; off >>= 1) s += __shfl_xor(s, off, 64);
    float mu = s * (1.f / HID);
    float d2 = 0.f;
#pragma unroll
    for (int i = 0; i < 4; ++i) { float d = v[i] - mu; d2 += d * d; }
#pragma unroll
    for (int off = 32; off; off >>= 1) d2 += __shfl_xor(d2, off, 64);
    float rstd = rsqrtf(d2 * (1.f / HID) + 1e-5f);
#pragma unroll
    for (int i = 0; i < 4; ++i) {
        int c = lane + 64 * i;
        float o = (v[i] - mu) * rstd * __bfloat162float(g[c]) + __bfloat162float(bta[c]);
        y[(long)row * HID + c] = __float2bfloat16(o);
    }
}

// =====================================================================
// GAT edge-softmax + aggregate, dense-adjacency form. One block per batch.
// resid[b,t,:] += sum_s alpha[t,s] * h[b,s,head,:]  (+ bgat), concat heads.
// =====================================================================
__global__ __launch_bounds__(256) void gat_kernel(
    const float* __restrict__ h, const float* __restrict__ adj,
    const __hip_bfloat16* __restrict__ sp, int l, float* __restrict__ resid) {
    __shared__ float hs[NTOK][HID];       // 50 KB
    __shared__ float adjs[NTOK][NTOK];
    __shared__ float als[NTOK][HEADS], ald[NTOK][HEADS];
    __shared__ float walpha[HEADS][64];
    __shared__ float attS[HID], attD[HID], bg[HID];
    int b = blockIdx.x, tid = threadIdx.x;
    const float* hb = h + (long)b * (NTOK * HID);
    for (int i = tid; i < NTOK * HID; i += 256) ((float*)hs)[i] = hb[i];
    for (int i = tid; i < NTOK * NTOK; i += 256) ((float*)adjs)[i] = adj[i];
    attS[tid] = __bfloat162float(sp[OFF_ASRC + l * HID + tid]);
    attD[tid] = __bfloat162float(sp[OFF_ADST + l * HID + tid]);
    bg[tid]   = __bfloat162float(sp[OFF_BGAT + l * HID + tid]);
    __syncthreads();
    for (int pr = tid; pr < NTOK * HEADS; pr += 256) {   // attention logits
        int s = pr >> 3, hh = pr & 7;
        float a1 = 0.f, a2 = 0.f;
        for (int d = 0; d < DH; ++d) {
            float hv = hs[s][hh * DH + d];
            a1 += hv * attS[hh * DH + d];
            a2 += hv * attD[hh * DH + d];
        }
        als[s][hh] = a1; ald[s][hh] = a2;
    }
    __syncthreads();
    int hd = tid >> 5, lane = tid & 31;
    float* res = resid + (long)b * (NTOK * HID);
    for (int t = 0; t < NTOK; ++t) {
        float aldt = ald[t][hd];
        float m0 = adjs[t][lane];
        float m1 = (lane + 32 < NTOK) ? adjs[t][lane + 32] : 0.f;
        float l0 = -1e30f, l1 = -1e30f;
        if (m0 > 0.f) { float e = als[lane][hd] + aldt; l0 = (e > 0.f) ? e : 0.2f * e; }
        if (m1 > 0.f) { float e = als[lane + 32][hd] + aldt; l1 = (e > 0.f) ? e : 0.2f * e; }
        float mx = fmaxf(l0, l1);
#pragma unroll
        for (int off = 16; off; off >>= 1) mx = fmaxf(mx, __shfl_xor(mx, off, 32));
        float w0 = m0 * expf(l0 - mx);
        float w1 = m1 * expf(l1 - mx);
        float sm = w0 + w1;
#pragma unroll
        for (int off = 16; off; off >>= 1) sm += __shfl_xor(sm, off, 32);
        float inv = 1.f / (sm + 1e-16f);
        walpha[hd][lane] = w0 * inv;
        if (lane + 32 < NTOK) walpha[hd][lane + 32] = w1 * inv;
        __syncthreads();
        float acc = 0.f;
        for (int s = 0; s < NTOK; ++s) acc += walpha[hd][s] * hs[s][hd * DH + lane];
        res[t * HID + hd * DH + lane] += acc + bg[hd * DH + lane];
        __syncthreads();
    }
}

// =====================================================================
__global__ void extract_cls(const float* __restrict__ resid, __hip_bfloat16* __restrict__ xb) {
    int idx = blockIdx.x * 256 + threadIdx.x;   // < 256*256
    int b = idx >> 8, n = idx & 255;
    xb[idx] = __float2bfloat16(resid[(long)b * (NTOK * HID) + n]);
}

__global__ __launch_bounds__(256) void softmax_kernel(
    const float* __restrict__ logits, const unsigned short* tag, void* __restrict__ out) {
    __shared__ float red[8];
    bool bf = tag_is_bf16(tag);
    int b = blockIdx.x, tid = threadIdx.x;
    const float* Lr = logits + (long)b * OUTD;
    float v[4], mx = -1e30f;
#pragma unroll
    for (int i = 0; i < 4; ++i) {
        int j = tid + i * 256;
        v[i] = (j < OUTD) ? Lr[j] : -1e30f;
        mx = fmaxf(mx, v[i]);
    }
#pragma unroll
    for (int off = 32; off; off >>= 1) mx = fmaxf(mx, __shfl_xor(mx, off, 64));
    if ((tid & 63) == 0) red[tid >> 6] = mx;
    __syncthreads();
    mx = fmaxf(fmaxf(red[0], red[1]), fmaxf(red[2], red[3]));
    float s = 0.f, ex[4];
#pragma unroll
    for (int i = 0; i < 4; ++i) {
        int j = tid + i * 256;
        ex[i] = (j < OUTD) ? expf(v[i] - mx) : 0.f;
        s += ex[i];
    }
#pragma unroll
    for (int off = 32; off; off >>= 1) s += __shfl_xor(s, off, 64);
    __syncthreads();
    if ((tid & 63) == 0) red[4 + (tid >> 6)] = s;
    __syncthreads();
    float inv = 1.f / (red[4] + red[5] + red[6] + red[7]);
#pragma unroll
    for (int i = 0; i < 4; ++i) {
        int j = tid + i * 256;
        if (j < OUTD) {
            float o = ex[i] * inv;
            if (bf) ((__hip_bfloat16*)out)[(long)b * OUTD + j] = __float2bfloat16(o);
            else    ((float*)out)[(long)b * OUTD + j] = o;
        }
    }
}

// =====================================================================
extern "C" void kernel_launch(void* const* d_in, const int* in_sizes, int n_in,
                              void* d_out, int out_size, void* d_ws, size_t ws_size,
                              hipStream_t stream) {
    const void* images = d_in[0];
    const int*  ei     = (const int*)d_in[1];
    const unsigned short* tag = (const unsigned short*)d_in[9];  // ln1_g (all ones)
    int E0 = in_sizes[1] / 2;

    char* p = (char*)d_ws;
    auto alloc = [&](size_t bytes) { char* r = p; p += (bytes + 255) & ~(size_t)255; return r; };
    float*          resid  = (float*)alloc((size_t)MROWS * HID * 4);       // 12.8 MB
    float*          hbuf   = (float*)alloc((size_t)MROWS * HID * 4);       // 12.8 MB
    __hip_bfloat16* xb     = (__hip_bfloat16*)alloc((size_t)MROWS * HID * 2);
    __hip_bfloat16* mid    = (__hip_bfloat16*)alloc((size_t)MROWS * MLPD * 2);
    float*          logits = (float*)alloc((size_t)BATCH * OUTD * 4);
    float*          pe     = (float*)alloc((size_t)NTOK * HID * 4);
    float*          adj    = (float*)alloc((size_t)NTOK * NTOK * 4);
    __hip_bfloat16* smallp = (__hip_bfloat16*)alloc((size_t)SP_TOTAL * 2);
    __hip_bfloat16* wmapT  = (__hip_bfloat16*)alloc((size_t)KPATCH * HID * 2);
    __hip_bfloat16* wgatT  = (__hip_bfloat16*)alloc((size_t)NBLK * HID * HID * 2);
    __hip_bfloat16* w1T    = (__hip_bfloat16*)alloc((size_t)NBLK * HID * MLPD * 2);
    __hip_bfloat16* w2T    = (__hip_bfloat16*)alloc((size_t)NBLK * HID * MLPD * 2);
    __hip_bfloat16* woutT  = (__hip_bfloat16*)alloc((size_t)HID * OUTD * 2);

    SmallSrc ss = { d_in[3], d_in[4], d_in[6], d_in[7], d_in[8], d_in[9], d_in[10],
                    d_in[11], d_in[12], d_in[14], d_in[16], d_in[18] };
    prep_kernel<<<51, 64, 0, stream>>>(ei, E0, adj, pe);
    pack_params<<<(SP_TOTAL + 255) / 256, 256, 0, stream>>>(ss, tag, smallp);
    transpose_kernel<<<13288, 256, 0, stream>>>(d_in[2], d_in[5], d_in[13], d_in[15],
                                                d_in[17], tag,
                                                wmapT, wgatT, w1T, w2T, woutT);
    patch_gemm_kernel<<<dim3(MPATCH / 64, HID / 64), 256, 0, stream>>>(
        images, wmapT, smallp, tag, resid);
    finish_tokens<<<MROWS, 256, 0, stream>>>(smallp, pe, resid);

    for (int l = 0; l < NBLK; ++l) {
        ln_kernel<<<MROWS / 4, 256, 0, stream>>>(resid, smallp + OFF_LN1G + l * HID,
                                                 smallp + OFF_LN1B + l * HID, xb);
        gemm_kernel<0><<<dim3(MROWS / 64, HID / 64), 256, 0, stream>>>(
            xb, wgatT + l * HID * HID, nullptr, hbuf, nullptr, MROWS, HID, HID);
        gat_kernel<<<BATCH, 256, 0, stream>>>(hbuf, adj, smallp, l, resid);
        ln_kernel<<<MROWS / 4, 256, 0, stream>>>(resid, smallp + OFF_LN2G + l * HID,
                                                 smallp + OFF_LN2B + l * HID, xb);
        gemm_kernel<2><<<dim3(MROWS / 64, MLPD / 64), 256, 0, stream>>>(
            xb, w1T + l * HID * MLPD, smallp + OFF_B1 + l * MLPD, nullptr, mid,
            MROWS, MLPD, HID);
        gemm_kernel<3><<<dim3(MROWS / 64, HID / 64), 256, 0, stream>>>(
            mid, w2T + l * HID * MLPD, smallp + OFF_B2 + l * HID, resid, nullptr,
            MROWS, HID, MLPD);
    }

    extract_cls<<<BATCH, 256, 0, stream>>>(resid, xb);
    gemm_kernel<1><<<dim3(BATCH / 64, (OUTD + 63) / 64), 256, 0, stream>>>(
        xb, woutT, smallp + OFF_BOUT, logits, nullptr, BATCH, OUTD, HID);
    softmax_kernel<<<BATCH, 256, 0, stream>>>(logits, tag, (__hip_bfloat16*)d_out);
}